// Round 2
// baseline (1946.019 us; speedup 1.0000x reference)
//
#include <hip/hip_runtime.h>
#include <hip/hip_cooperative_groups.h>
#include <math.h>

namespace cg = cooperative_groups;

// Problem: SEQ_LEN=512, BATCH=64, INPUT=256, HIDDEN=512. fp32 in/out.
#define TT 512
#define BB 64
#define II 256
#define HH 512

#define NTHREADS 512        // 8 waves
#define NGRP 4              // batch groups (16 rows each)
#define NCT  16             // h-tile blocks per group (32 h-units each)
#define NBLOCKS (NGRP*NCT)  // 64 blocks total

#define KPAD 776            // f16 elements per A row (768 + 8 pad)

typedef _Float16 f16x8 __attribute__((ext_vector_type(8)));
typedef _Float16 f16x4 __attribute__((ext_vector_type(4)));
typedef float    f32x4 __attribute__((ext_vector_type(4)));

__device__ __forceinline__ float sig_(float v)  { return 1.0f / (1.0f + __expf(-v)); }
__device__ __forceinline__ float tanh_(float v) { float e = __expf(2.0f * v); return 1.0f - 2.0f / (e + 1.0f); }

// Workgroup barrier that drains ONLY lgkmcnt (LDS) — no vmcnt(0), so in-flight
// global stores (h publish -> MALL, out -> HBM) never enter the critical chain.
__device__ __forceinline__ void barrier_lds() {
    __builtin_amdgcn_sched_barrier(0);
    asm volatile("s_waitcnt lgkmcnt(0)" ::: "memory");
    __builtin_amdgcn_s_barrier();
    __builtin_amdgcn_sched_barrier(0);
}

__global__ void __launch_bounds__(NTHREADS, 2)
lstm_wflag(const float* __restrict__ x,
           const float* __restrict__ Wx,
           const float* __restrict__ bx,
           const float* __restrict__ Wh,
           const float* __restrict__ bh,
           float* __restrict__ out,
           unsigned int* __restrict__ flags,   // [NGRP][128] u32 per-WAVE epochs
           unsigned int* __restrict__ hbuf)    // [2][BB][256] u32 = packed f16 pairs
{
    // Double-buffered A tile (x | h) so ONE barrier/step suffices.
    __shared__ __align__(16) _Float16 AL[2][16 * KPAD];   // 2 x 24,832 B
    __shared__ __align__(16) float    exch[8 * 16 * 20];  // per-wave gate exchange

    cg::grid_group grid = cg::this_grid();

    const int blk  = blockIdx.x;
    const int grp  = blk & 3;          // batch group (16 rows)
    const int b0   = grp * 16;
    const int ct   = blk >> 2;         // 0..15, h-units [ct*32, ct*32+32)
    const int hblk = ct * 32;

    const int tid = threadIdx.x;
    const int wv  = tid >> 6;          // wave 0..7
    const int L   = tid & 63;
    const int n   = L & 15;            // MFMA A-row m / B-col n
    const int qd  = L >> 4;            // lane quad -> k = qd*8..qd*8+7

    // ---- Preload B fragments into registers; constant across ALL 512 steps ----
    const int g  = n & 3;
    const int hu = hblk + wv * 4 + (n >> 2);
    f16x8 bfr[24];
    #pragma unroll
    for (int kc = 0; kc < 24; ++kc) {
        int k0 = kc * 32 + qd * 8;
        const float* src = (kc < 8)
            ? (Wx + ((size_t)g * HH + hu) * II + k0)
            : (Wh + ((size_t)g * HH + hu) * HH + (k0 - 256));
        float4 u0 = ((const float4*)src)[0];
        float4 u1 = ((const float4*)src)[1];
        f16x8 b = { (_Float16)u0.x, (_Float16)u0.y, (_Float16)u0.z, (_Float16)u0.w,
                    (_Float16)u1.x, (_Float16)u1.y, (_Float16)u1.z, (_Float16)u1.w };
        bfr[kc] = b;
    }

    // Epilogue ownership: lane -> (batch be, h-unit he)
    const int be  = L >> 2;
    const int hle = L & 3;
    const int he  = hblk + wv * 4 + hle;
    float bias4[4];
    #pragma unroll
    for (int g2 = 0; g2 < 4; ++g2) bias4[g2] = bx[g2 * HH + he] + bh[g2 * HH + he];

    // ---- Zero the group's wave-flags (16 blocks race writing 0: benign) ----
    if (tid < 128)
        __hip_atomic_store(&flags[grp * 128 + tid], 0u,
                           __ATOMIC_RELAXED, __HIP_MEMORY_SCOPE_AGENT);
    grid.sync();   // all flags zeroed before anyone can poll

    const size_t HSEQ = (size_t)TT * BB * HH;
    float c_state = 0.0f;
    float* exchW = &exch[wv * 16 * 20];
    const int myflag = grp * 128 + ct * 8 + wv;   // this wave's flag slot

    for (int t = 0; t < TT; ++t) {
        const int p = t & 1;
        _Float16* ALp = AL[p];

        // ---- Stage x_t into x-part of current A buffer (no h dependence) ----
        #pragma unroll
        for (int i = 0; i < 2; ++i) {
            int ch = tid + i * NTHREADS;           // 0..1023
            int row = ch >> 6, pos = ch & 63;
            float4 v = ((const float4*)(x + ((size_t)t * BB + b0 + row) * II))[pos];
            f16x4 pk = { (_Float16)v.x, (_Float16)v.y, (_Float16)v.z, (_Float16)v.w };
            *(f16x4*)&ALp[row * KPAD + pos * 4] = pk;
        }

        if (t > 0) {
            // ---- EVERY wave polls the 128 per-wave flags (512 B, 8 lines) ----
            // so each wave can proceed straight to its h-loads: no extra barrier.
            const unsigned long long* fp =
                (const unsigned long long*)(flags + grp * 128);
            const unsigned tu = (unsigned)t;
            for (;;) {
                unsigned long long f2 = __hip_atomic_load(
                    &fp[L], __ATOMIC_RELAXED, __HIP_MEMORY_SCOPE_AGENT);
                unsigned lo = (unsigned)f2, hi = (unsigned)(f2 >> 32);
                if (__all((int)(lo >= tu && hi >= tu))) break;
                __builtin_amdgcn_s_sleep(1);
            }
            asm volatile("" ::: "memory");   // compile-order: loads below stay below

            // ---- Stage h_{t-1} rows b0..b0+15 (4 x 8B per thread) ----
            const unsigned long long* hsrc =
                (const unsigned long long*)(hbuf + (size_t)p * (BB * 256));
            #pragma unroll
            for (int i = 0; i < 4; ++i) {
                int ch = tid + i * NTHREADS;       // 0..2047
                int row = ch >> 7, pos = ch & 127;
                unsigned long long u = __hip_atomic_load(
                    hsrc + (size_t)(b0 + row) * 128 + pos,
                    __ATOMIC_RELAXED, __HIP_MEMORY_SCOPE_AGENT);
                *(unsigned long long*)((char*)ALp + row * (KPAD * 2) + II * 2 + pos * 8) = u;
            }
        }

        // ---- Single barrier per step (LDS-only drain; stores stay in flight) ----
        barrier_lds();

        // ---- MFMA: full K=768, two accumulator chains for ILP ----
        const char* Ab = (const char*)ALp + n * (KPAD * 2) + qd * 16;
        f32x4 a0 = { 0.f, 0.f, 0.f, 0.f };
        f32x4 a1 = { 0.f, 0.f, 0.f, 0.f };
        #pragma unroll
        for (int kc = 0; kc < 8; ++kc) {           // x-part
            f16x8 a = *(const f16x8*)(Ab + kc * 64);
            if (kc & 1) a1 = __builtin_amdgcn_mfma_f32_16x16x32_f16(a, bfr[kc], a1, 0, 0, 0);
            else        a0 = __builtin_amdgcn_mfma_f32_16x16x32_f16(a, bfr[kc], a0, 0, 0, 0);
        }
        if (t > 0) {
            #pragma unroll
            for (int kc = 8; kc < 24; ++kc) {      // h-part
                f16x8 a = *(const f16x8*)(Ab + kc * 64);
                if (kc & 1) a1 = __builtin_amdgcn_mfma_f32_16x16x32_f16(a, bfr[kc], a1, 0, 0, 0);
                else        a0 = __builtin_amdgcn_mfma_f32_16x16x32_f16(a, bfr[kc], a0, 0, 0, 0);
            }
        }
        f32x4 acc = a0 + a1;

        // ---- Intra-wave exchange: C[row=qd*4+r][col=n] -> gates per (b,h) ----
        #pragma unroll
        for (int r = 0; r < 4; ++r)
            exchW[(qd * 4 + r) * 20 + n] = acc[r];
        // same wave writes then reads: lockstep + in-order DS, no barrier needed
        float4 pre4 = *(const float4*)&exchW[be * 20 + hle * 4];

        // ---- Gates; c_state in-register ----
        float pf = pre4.x + bias4[0];
        float pi = pre4.y + bias4[1];
        float po = pre4.z + bias4[2];
        float pc = pre4.w + bias4[3];
        float fg = sig_(pf), ig = sig_(pi), og = sig_(po);
        float cn = fg * c_state + ig * tanh_(pc);
        float hv = og * tanh_(cn);
        c_state = cn;

        // ---- Publish h_t FIRST (packed f16 pairs), then per-WAVE flag ----
        {
            union { _Float16 f; unsigned short u; } cv; cv.f = (_Float16)hv;
            unsigned mine  = cv.u;
            unsigned other = (unsigned)__shfl_xor((int)mine, 1, 64);
            if ((hle & 1) == 0) {
                unsigned pk = mine | (other << 16);
                unsigned int* hdst = hbuf + (size_t)((t + 1) & 1) * (BB * 256);
                __hip_atomic_store(&hdst[(unsigned)(b0 + be) * 256 + (unsigned)(he >> 1)],
                                   pk, __ATOMIC_RELAXED, __HIP_MEMORY_SCOPE_AGENT);
            }
        }

        // Wave-local ordering: drain THIS wave's stores (h-pairs ~MALL ack only;
        // the out store below is issued AFTER the flag so it never sits here),
        // then lane 0 publishes the wave's epoch.
        __builtin_amdgcn_sched_barrier(0);
        asm volatile("s_waitcnt vmcnt(0)" ::: "memory");
        __builtin_amdgcn_sched_barrier(0);
        if (t != TT - 1 && L == 0)
            __hip_atomic_store(&flags[myflag], (unsigned)(t + 1),
                               __ATOMIC_RELAXED, __HIP_MEMORY_SCOPE_AGENT);

        // ---- out stores AFTER the flag: their HBM ack is off the chain ----
        out[((size_t)t * BB + b0 + be) * HH + he] = hv;
        if (t == TT - 1) {
            size_t r = (size_t)(b0 + be) * HH + he;
            out[HSEQ + r] = hv;                        // h_last
            out[HSEQ + (size_t)BB * HH + r] = cn;      // c_last
        }
        // no trailing barrier: A tile is double-buffered; a wave entering step
        // t+1 writes AL[p^1], which every wave finished reading before THIS
        // step's barrier. Cross-block WAR on hbuf[p^1] is guarded by flags:
        // flag>=t implies that block finished its step t-1 reads of hbuf[p^1].
    }
}

extern "C" void kernel_launch(void* const* d_in, const int* in_sizes, int n_in,
                              void* d_out, int out_size, void* d_ws, size_t ws_size,
                              hipStream_t stream)
{
    const float* x  = (const float*)d_in[0];
    const float* Wx = (const float*)d_in[1];
    const float* bx = (const float*)d_in[2];
    const float* Wh = (const float*)d_in[3];
    const float* bh = (const float*)d_in[4];
    float* out = (float*)d_out;

    // ws: [0,4KB) per-wave epoch flags [NGRP][128]; [4KB, 4KB+128KB) h ping-pong
    unsigned int* flags = (unsigned int*)d_ws;
    unsigned int* hbuf  = (unsigned int*)((char*)d_ws + 4096);

    void* args[] = { (void*)&x, (void*)&Wx, (void*)&bx, (void*)&bh, // placeholder fixed below
                     (void*)&bh, (void*)&out, (void*)&flags, (void*)&hbuf };
    // (correct arg order)
    void* args2[] = { (void*)&x, (void*)&Wx, (void*)&bx, (void*)&Wh, (void*)&bh,
                      (void*)&out, (void*)&flags, (void*)&hbuf };
    (void)args;
    hipLaunchCooperativeKernel((const void*)lstm_wflag,
                               dim3(NBLOCKS), dim3(NTHREADS),
                               args2, 0, stream);
}